// Round 2
// baseline (948.899 us; speedup 1.0000x reference)
//
#include <hip/hip_runtime.h>
#include <hip/hip_bf16.h>
#include <cstdint>

typedef __bf16 bf16x8 __attribute__((ext_vector_type(8)));
typedef float  f32x4  __attribute__((ext_vector_type(4)));

__device__ __forceinline__ unsigned short f2bf(float f) {
    union { float f; uint32_t u; } v; v.f = f;
    uint32_t r = (v.u + 0x7FFFu + ((v.u >> 16) & 1u)) >> 16;
    return (unsigned short)r;
}

__device__ __forceinline__ float fast_tanh(float x) {
    x = fminf(10.f, fmaxf(-10.f, x));
    float e = __expf(2.f * x);
    return (e - 1.f) / (e + 1.f);
}

__device__ __forceinline__ float gelu_exact(float x) {
    return 0.5f * x * (1.0f + erff(x * 0.70710678118654752f));
}

// ---------------------------------------------------------------------------
// Weight conversion: W0 [512,1024] -> bf16; Wbx = Wb[:, :512] -> bf16
// ---------------------------------------------------------------------------
__global__ __launch_bounds__(256) void convert_weights_kernel(
    const float* __restrict__ W0, const float* __restrict__ Wb,
    unsigned short* __restrict__ W0bf, unsigned short* __restrict__ Wbxbf)
{
    int i = blockIdx.x * 256 + threadIdx.x;
    if (i < 512 * 1024) W0bf[i] = f2bf(W0[i]);
    if (i < 128 * 512) {
        int n = i >> 9, k = i & 511;
        Wbxbf[i] = f2bf(Wb[n * 544 + k]);
    }
}

// ---------------------------------------------------------------------------
// bf16 MFMA GEMM, 128x128 tile, BK=32, 256 threads (4 waves, 2x2 of 64x64).
// A: [M,K] (fp32 converted on the fly, or bf16), B: [N,K] bf16 (B^T form).
// C = epilogue(A@B^T + bias):  GELU->bf16 (gemm1)  or  +bias->fp32 (gemm2).
// ---------------------------------------------------------------------------
template <int NT, bool A_F32, bool GELU_OUT>
__global__ __launch_bounds__(256) void gemm_kernel(
    const void* __restrict__ Aptr, const unsigned short* __restrict__ B,
    const float* __restrict__ bias, void* __restrict__ Cptr,
    int M, int N, int K)
{
    __shared__ alignas(16) unsigned short Als[128 * 32];
    __shared__ alignas(16) unsigned short Bls[128 * 32];

    const int bid = blockIdx.x;
    const int nb = bid & (NT - 1);
    const int mb = bid / NT;
    const int m0 = mb * 128;
    const int n0 = nb * 128;

    const int t = threadIdx.x;
    const int w = t >> 6, l = t & 63;
    const int wr = w >> 1, wc = w & 1;
    const int lr = l & 15, lk = (l >> 4) * 8;

    f32x4 acc[4][4];
    const f32x4 zero = {0.f, 0.f, 0.f, 0.f};
#pragma unroll
    for (int i = 0; i < 4; ++i)
#pragma unroll
        for (int j = 0; j < 4; ++j) acc[i][j] = zero;

    for (int k0 = 0; k0 < K; k0 += 32) {
        // ---- stage A tile [128][32]
        if constexpr (A_F32) {
            const float* A = (const float*)Aptr;
#pragma unroll
            for (int p = 0; p < 4; ++p) {
                int r = p * 32 + (t >> 3);
                int kq = (t & 7) * 4;
                float4 v = *reinterpret_cast<const float4*>(
                    &A[(size_t)(m0 + r) * K + k0 + kq]);
                ushort4 o;
                o.x = f2bf(v.x); o.y = f2bf(v.y);
                o.z = f2bf(v.z); o.w = f2bf(v.w);
                *reinterpret_cast<ushort4*>(&Als[r * 32 + kq]) = o;
            }
        } else {
            const unsigned short* A = (const unsigned short*)Aptr;
#pragma unroll
            for (int p = 0; p < 2; ++p) {
                int r = p * 64 + (t >> 2);
                int kq = (t & 3) * 8;
                *reinterpret_cast<uint4*>(&Als[r * 32 + kq]) =
                    *reinterpret_cast<const uint4*>(&A[(size_t)(m0 + r) * K + k0 + kq]);
            }
        }
        // ---- stage B tile [128][32]
#pragma unroll
        for (int p = 0; p < 2; ++p) {
            int r = p * 64 + (t >> 2);
            int kq = (t & 3) * 8;
            *reinterpret_cast<uint4*>(&Bls[r * 32 + kq]) =
                *reinterpret_cast<const uint4*>(&B[(size_t)(n0 + r) * K + k0 + kq]);
        }
        __syncthreads();

        bf16x8 af[4], bfr[4];
#pragma unroll
        for (int i = 0; i < 4; ++i)
            af[i] = *reinterpret_cast<const bf16x8*>(&Als[(wr * 64 + i * 16 + lr) * 32 + lk]);
#pragma unroll
        for (int j = 0; j < 4; ++j)
            bfr[j] = *reinterpret_cast<const bf16x8*>(&Bls[(wc * 64 + j * 16 + lr) * 32 + lk]);
#pragma unroll
        for (int i = 0; i < 4; ++i)
#pragma unroll
            for (int j = 0; j < 4; ++j)
                acc[i][j] = __builtin_amdgcn_mfma_f32_16x16x32_bf16(
                    af[i], bfr[j], acc[i][j], 0, 0, 0);
        __syncthreads();
    }

    // ---- epilogue: C/D layout col=lane&15, row=(lane>>4)*4+reg
#pragma unroll
    for (int i = 0; i < 4; ++i) {
#pragma unroll
        for (int j = 0; j < 4; ++j) {
            int col = n0 + wc * 64 + j * 16 + (l & 15);
            int rowb = m0 + wr * 64 + i * 16 + (l >> 4) * 4;
            float bv = bias[col];
#pragma unroll
            for (int p = 0; p < 4; ++p) {
                float v = acc[i][j][p] + bv;
                size_t idx = (size_t)(rowb + p) * N + col;
                if constexpr (GELU_OUT) {
                    ((unsigned short*)Cptr)[idx] = f2bf(gelu_exact(v));
                } else {
                    ((float*)Cptr)[idx] = v;
                }
            }
        }
    }
}

// ---------------------------------------------------------------------------
// Recurrent scan: 128 blocks (one batch element), 512 threads.
// pre_g[b,t,u] already holds h0[b,t,:]@Wbx^T + bb.  Weights in registers.
// Per step: g = 1.7159*tanh(0.666*(pre_g + Wbh@h)); heads = Wcat@g + bias;
//           h' = ff1 + sig(ta+tb)*(ff2-ff1);  seq[b,t,:] = h'
// ---------------------------------------------------------------------------
__global__ __launch_bounds__(512) void scan_kernel(
    const float* __restrict__ pre_g, const float* __restrict__ Wb,
    const float* __restrict__ Wff1, const float* __restrict__ bff1,
    const float* __restrict__ Wff2, const float* __restrict__ bff2,
    const float* __restrict__ Wta,  const float* __restrict__ bta,
    const float* __restrict__ Wtb,  const float* __restrict__ btb,
    float* __restrict__ seq)
{
    __shared__ alignas(16) float h_lds[32];
    __shared__ alignas(16) float g_lds[144];   // padded: idx = k + (k>>5)*4
    __shared__ alignas(16) float head_lds[128];

    const int tid = threadIdx.x;
    const int b = blockIdx.x;
    const int u = tid >> 2;   // 0..127
    const int q = tid & 3;

    // backbone weights Wbh[u][q*8 .. +8]  (Wb columns 512..543)
    float wbh[8];
#pragma unroll
    for (int j = 0; j < 8; ++j) wbh[j] = Wb[u * 544 + 512 + q * 8 + j];

    // head weights: unit o=u; which=o>>5 in {ff1,ff2,ta,tb}; row (o&31), cols q*32..+32
    const int which = u >> 5;
    const int uu = u & 31;
    const float* Wh = (which == 0) ? Wff1 : (which == 1) ? Wff2 : (which == 2) ? Wta : Wtb;
    const float* bh = (which == 0) ? bff1 : (which == 1) ? bff2 : (which == 2) ? bta : btb;
    float whr[32];
#pragma unroll
    for (int j4 = 0; j4 < 8; ++j4) {
        float4 v = *reinterpret_cast<const float4*>(&Wh[uu * 128 + q * 32 + j4 * 4]);
        whr[j4 * 4 + 0] = v.x; whr[j4 * 4 + 1] = v.y;
        whr[j4 * 4 + 2] = v.z; whr[j4 * 4 + 3] = v.w;
    }
    const float hbias = bh[uu];

    if (tid < 32) h_lds[tid] = 0.0f;
    __syncthreads();

    const size_t base = (size_t)b * 512 * 128;
    const size_t sbase = (size_t)b * 512 * 32;
    float pg0 = pre_g[base + u];
    float pg1 = pre_g[base + 128 + u];

    for (int step = 0; step < 512; ++step) {
        float pg2 = 0.f;
        if (step + 2 < 512) pg2 = pre_g[base + (size_t)(step + 2) * 128 + u];

        // ---- backbone: partial dot over h[q*8 .. +8]
        float s = 0.f;
#pragma unroll
        for (int j2 = 0; j2 < 2; ++j2) {
            float4 hv = *reinterpret_cast<const float4*>(&h_lds[q * 8 + j2 * 4]);
            s = fmaf(wbh[j2 * 4 + 0], hv.x, s);
            s = fmaf(wbh[j2 * 4 + 1], hv.y, s);
            s = fmaf(wbh[j2 * 4 + 2], hv.z, s);
            s = fmaf(wbh[j2 * 4 + 3], hv.w, s);
        }
        s += __shfl_xor(s, 1);
        s += __shfl_xor(s, 2);
        float g = 1.7159f * fast_tanh(0.666f * (pg0 + s));
        if (q == 0) g_lds[u + ((u >> 5) << 2)] = g;
        __syncthreads();

        // ---- heads: partial dot over g[q*32 .. +32] (padded layout, bank-safe)
        float d = 0.f;
        const float* gq = &g_lds[q * 36];
#pragma unroll
        for (int j4 = 0; j4 < 8; ++j4) {
            float4 gv = *reinterpret_cast<const float4*>(&gq[j4 * 4]);
            d = fmaf(whr[j4 * 4 + 0], gv.x, d);
            d = fmaf(whr[j4 * 4 + 1], gv.y, d);
            d = fmaf(whr[j4 * 4 + 2], gv.z, d);
            d = fmaf(whr[j4 * 4 + 3], gv.w, d);
        }
        d += __shfl_xor(d, 1);
        d += __shfl_xor(d, 2);
        d += hbias;
        if (u < 64) d = fast_tanh(d);   // ff1, ff2 get tanh; ta, tb stay raw
        if (q == 0) head_lds[u] = d;
        __syncthreads();

        // ---- combine + state update + seq store
        if (tid < 32) {
            float ff1 = head_lds[tid], ff2 = head_lds[32 + tid];
            float ta = head_lds[64 + tid], tb = head_lds[96 + tid];
            float ti = 1.0f / (1.0f + __expf(-(ta + tb)));
            float hn = ff1 + ti * (ff2 - ff1);
            h_lds[tid] = hn;
            seq[sbase + (size_t)step * 32 + tid] = hn;
        }
        __syncthreads();

        pg0 = pg1; pg1 = pg2;
    }
}

// ---------------------------------------------------------------------------
// Final: y=gelu(seq); logits=y@W2^T+b2; max over T; softmax -> out [128,3]
// ---------------------------------------------------------------------------
__global__ __launch_bounds__(256) void final_kernel(
    const float* __restrict__ seq, const float* __restrict__ W2,
    const float* __restrict__ b2, float* __restrict__ out)
{
    const int b = blockIdx.x, tid = threadIdx.x;
    __shared__ float w2s[96];
    __shared__ float redbuf[12];
    if (tid < 96) w2s[tid] = W2[tid];
    __syncthreads();

    float m0 = -1e30f, m1 = -1e30f, m2 = -1e30f;
    for (int t = tid; t < 512; t += 256) {
        const float* row = &seq[(size_t)(b * 512 + t) * 32];
        float l0 = 0.f, l1 = 0.f, l2 = 0.f;
#pragma unroll
        for (int u4 = 0; u4 < 8; ++u4) {
            float4 v = *reinterpret_cast<const float4*>(&row[u4 * 4]);
            float xs[4] = {v.x, v.y, v.z, v.w};
#pragma unroll
            for (int e = 0; e < 4; ++e) {
                float y = gelu_exact(xs[e]);
                int uidx = u4 * 4 + e;
                l0 = fmaf(y, w2s[uidx], l0);
                l1 = fmaf(y, w2s[32 + uidx], l1);
                l2 = fmaf(y, w2s[64 + uidx], l2);
            }
        }
        m0 = fmaxf(m0, l0); m1 = fmaxf(m1, l1); m2 = fmaxf(m2, l2);
    }
#pragma unroll
    for (int off = 32; off; off >>= 1) {
        m0 = fmaxf(m0, __shfl_xor(m0, off));
        m1 = fmaxf(m1, __shfl_xor(m1, off));
        m2 = fmaxf(m2, __shfl_xor(m2, off));
    }
    if ((tid & 63) == 0) {
        int wv = tid >> 6;
        redbuf[wv * 3 + 0] = m0; redbuf[wv * 3 + 1] = m1; redbuf[wv * 3 + 2] = m2;
    }
    __syncthreads();
    if (tid == 0) {
        float a0 = -1e30f, a1 = -1e30f, a2 = -1e30f;
        for (int i = 0; i < 4; ++i) {
            a0 = fmaxf(a0, redbuf[i * 3 + 0]);
            a1 = fmaxf(a1, redbuf[i * 3 + 1]);
            a2 = fmaxf(a2, redbuf[i * 3 + 2]);
        }
        a0 += b2[0]; a1 += b2[1]; a2 += b2[2];
        float mm = fmaxf(a0, fmaxf(a1, a2));
        float e0 = expf(a0 - mm), e1 = expf(a1 - mm), e2 = expf(a2 - mm);
        float inv = 1.0f / (e0 + e1 + e2);
        out[b * 3 + 0] = e0 * inv;
        out[b * 3 + 1] = e1 * inv;
        out[b * 3 + 2] = e2 * inv;
    }
}

// ---------------------------------------------------------------------------
extern "C" void kernel_launch(void* const* d_in, const int* in_sizes, int n_in,
                              void* d_out, int out_size, void* d_ws, size_t ws_size,
                              hipStream_t stream)
{
    const float* x    = (const float*)d_in[0];
    const float* W0   = (const float*)d_in[1];
    const float* b0   = (const float*)d_in[2];
    const float* Wb   = (const float*)d_in[3];
    const float* bb   = (const float*)d_in[4];
    const float* Wff1 = (const float*)d_in[5];
    const float* bff1 = (const float*)d_in[6];
    const float* Wff2 = (const float*)d_in[7];
    const float* bff2 = (const float*)d_in[8];
    const float* Wta  = (const float*)d_in[9];
    const float* bta  = (const float*)d_in[10];
    const float* Wtb  = (const float*)d_in[11];
    const float* btb  = (const float*)d_in[12];
    const float* W2   = (const float*)d_in[13];
    const float* b2   = (const float*)d_in[14];

    char* ws = (char*)d_ws;
    unsigned short* h0bf  = (unsigned short*)(ws);                 // 67,108,864 B
    float*          pre_g = (float*)(ws + 67108864);               // 33,554,432 B
    float*          seq   = (float*)(ws + 100663296);              //  8,388,608 B
    unsigned short* W0bf  = (unsigned short*)(ws + 109051904);     //  1,048,576 B
    unsigned short* Wbxbf = (unsigned short*)(ws + 110100480);     //    131,072 B
    (void)ws_size; (void)in_sizes; (void)n_in; (void)out_size;

    convert_weights_kernel<<<2048, 256, 0, stream>>>(W0, Wb, W0bf, Wbxbf);

    // h0 = gelu(x @ W0^T + b0)  -> bf16 [65536, 512]
    gemm_kernel<4, true, true><<<2048, 256, 0, stream>>>(
        (const void*)x, W0bf, b0, (void*)h0bf, 65536, 512, 1024);

    // pre_g = h0 @ Wbx^T + bb   -> fp32 [65536, 128]
    gemm_kernel<1, false, false><<<512, 256, 0, stream>>>(
        (const void*)h0bf, Wbxbf, bb, (void*)pre_g, 65536, 128, 512);

    scan_kernel<<<128, 512, 0, stream>>>(pre_g, Wb,
        Wff1, bff1, Wff2, bff2, Wta, bta, Wtb, btb, seq);

    final_kernel<<<128, 256, 0, stream>>>(seq, W2, b2, (float*)d_out);
}

// Round 4
// 907.902 us; speedup vs baseline: 1.0452x; 1.0452x over previous
//
#include <hip/hip_runtime.h>
#include <hip/hip_bf16.h>
#include <cstdint>

typedef __bf16 bf16x8 __attribute__((ext_vector_type(8)));
typedef float  f32x4  __attribute__((ext_vector_type(4)));

__device__ __forceinline__ unsigned short f2bf(float f) {
    union { float f; uint32_t u; } v; v.f = f;
    uint32_t r = (v.u + 0x7FFFu + ((v.u >> 16) & 1u)) >> 16;
    return (unsigned short)r;
}

__device__ __forceinline__ float fast_tanh(float x) {
    x = fminf(10.f, fmaxf(-10.f, x));
    float e = __expf(2.f * x);
    return (e - 1.f) / (e + 1.f);
}

__device__ __forceinline__ float gelu_exact(float x) {
    return 0.5f * x * (1.0f + erff(x * 0.70710678118654752f));
}

// ---------------------------------------------------------------------------
// Weight conversion (vectorized): W0 [512,1024] -> bf16; Wbx = Wb[:, :512] -> bf16
// grid: 512 blocks x 256 threads; i indexes float4 groups
// ---------------------------------------------------------------------------
__global__ __launch_bounds__(256) void convert_weights_kernel(
    const float* __restrict__ W0, const float* __restrict__ Wb,
    unsigned short* __restrict__ W0bf, unsigned short* __restrict__ Wbxbf)
{
    int i = blockIdx.x * 256 + threadIdx.x;
    if (i < 131072) {                       // 524288 / 4
        float4 v = reinterpret_cast<const float4*>(W0)[i];
        ushort4 o;
        o.x = f2bf(v.x); o.y = f2bf(v.y); o.z = f2bf(v.z); o.w = f2bf(v.w);
        reinterpret_cast<ushort4*>(W0bf)[i] = o;
    }
    if (i < 16384) {                        // 65536 / 4
        int n = i >> 7, k4 = i & 127;
        float4 v = *reinterpret_cast<const float4*>(&Wb[n * 544 + k4 * 4]);
        ushort4 o;
        o.x = f2bf(v.x); o.y = f2bf(v.y); o.z = f2bf(v.z); o.w = f2bf(v.w);
        reinterpret_cast<ushort4*>(Wbxbf)[i] = o;
    }
}

// ---------------------------------------------------------------------------
// bf16 MFMA GEMM, 128x128 tile, BK=64, 256 threads (4 waves, 2x2 of 64x64).
// A: [M,K] (fp32 converted on the fly, or bf16), B: [N,K] bf16 (B^T form).
// C = epilogue(A@B^T + bias):  GELU->bf16 (gemm1)  or  +bias->fp32 (gemm2).
// ---------------------------------------------------------------------------
template <int NT, bool A_F32, bool GELU_OUT>
__global__ __launch_bounds__(256) void gemm_kernel(
    const void* __restrict__ Aptr, const unsigned short* __restrict__ B,
    const float* __restrict__ bias, void* __restrict__ Cptr,
    int M, int N, int K)
{
    __shared__ alignas(16) unsigned short Als[128 * 64];
    __shared__ alignas(16) unsigned short Bls[128 * 64];

    const int bid = blockIdx.x;
    const int nb = bid & (NT - 1);
    const int mb = bid / NT;
    const int m0 = mb * 128;
    const int n0 = nb * 128;

    const int t = threadIdx.x;
    const int w = t >> 6, l = t & 63;
    const int wr = w >> 1, wc = w & 1;
    const int lr = l & 15, lk = (l >> 4) * 8;

    f32x4 acc[4][4];
    const f32x4 zero = {0.f, 0.f, 0.f, 0.f};
#pragma unroll
    for (int i = 0; i < 4; ++i)
#pragma unroll
        for (int j = 0; j < 4; ++j) acc[i][j] = zero;

    for (int k0 = 0; k0 < K; k0 += 64) {
        // ---- stage A tile [128][64]
        if constexpr (A_F32) {
            const float* A = (const float*)Aptr;
#pragma unroll
            for (int p = 0; p < 8; ++p) {
                int r = p * 16 + (t >> 4);
                int kq = (t & 15) * 4;
                float4 v = *reinterpret_cast<const float4*>(
                    &A[(size_t)(m0 + r) * K + k0 + kq]);
                ushort4 o;
                o.x = f2bf(v.x); o.y = f2bf(v.y);
                o.z = f2bf(v.z); o.w = f2bf(v.w);
                *reinterpret_cast<ushort4*>(&Als[r * 64 + kq]) = o;
            }
        } else {
            const unsigned short* A = (const unsigned short*)Aptr;
#pragma unroll
            for (int p = 0; p < 4; ++p) {
                int idx = p * 256 + t;
                int r = idx >> 3, c = (idx & 7) * 8;
                *reinterpret_cast<uint4*>(&Als[r * 64 + c]) =
                    *reinterpret_cast<const uint4*>(&A[(size_t)(m0 + r) * K + k0 + c]);
            }
        }
        // ---- stage B tile [128][64]
#pragma unroll
        for (int p = 0; p < 4; ++p) {
            int idx = p * 256 + t;
            int r = idx >> 3, c = (idx & 7) * 8;
            *reinterpret_cast<uint4*>(&Bls[r * 64 + c]) =
                *reinterpret_cast<const uint4*>(&B[(size_t)(n0 + r) * K + k0 + c]);
        }
        __syncthreads();

#pragma unroll
        for (int kk = 0; kk < 64; kk += 32) {
            bf16x8 af[4], bfr[4];
#pragma unroll
            for (int i = 0; i < 4; ++i)
                af[i] = *reinterpret_cast<const bf16x8*>(
                    &Als[(wr * 64 + i * 16 + lr) * 64 + kk + lk]);
#pragma unroll
            for (int j = 0; j < 4; ++j)
                bfr[j] = *reinterpret_cast<const bf16x8*>(
                    &Bls[(wc * 64 + j * 16 + lr) * 64 + kk + lk]);
#pragma unroll
            for (int i = 0; i < 4; ++i)
#pragma unroll
                for (int j = 0; j < 4; ++j)
                    acc[i][j] = __builtin_amdgcn_mfma_f32_16x16x32_bf16(
                        af[i], bfr[j], acc[i][j], 0, 0, 0);
        }
        __syncthreads();
    }

    // ---- epilogue: C/D layout col=lane&15, row=(lane>>4)*4+reg
#pragma unroll
    for (int i = 0; i < 4; ++i) {
#pragma unroll
        for (int j = 0; j < 4; ++j) {
            int col = n0 + wc * 64 + j * 16 + (l & 15);
            int rowb = m0 + wr * 64 + i * 16 + (l >> 4) * 4;
            float bv = bias[col];
#pragma unroll
            for (int p = 0; p < 4; ++p) {
                float v = acc[i][j][p] + bv;
                size_t idx = (size_t)(rowb + p) * N + col;
                if constexpr (GELU_OUT) {
                    ((unsigned short*)Cptr)[idx] = f2bf(gelu_exact(v));
                } else {
                    ((float*)Cptr)[idx] = v;
                }
            }
        }
    }
}

// ---------------------------------------------------------------------------
// Recurrent scan v2: 128 blocks (one batch element), 512 threads, 2 barriers
// per step (was 3).  Stage 1: u=tid>>2, q=tid&3 computes g[u] (K=32 split 4).
// Stage 2: j=tid>>4, hh=(tid>>2)&3, q2=tid&3 computes head hh of unit j
// (K=128 split 4); the 4 head values of unit j live in one 16-lane group ->
// gather via shfl_xor(4/8/12), sigmoid+mix computed in-wave, no 3rd barrier.
// pre_g loaded in 8-step register chunks, one chunk ahead, to amortize the
// vmcnt(0) drain that __syncthreads forces.
// ---------------------------------------------------------------------------
__global__ __launch_bounds__(512) void scan_kernel(
    const float* __restrict__ pre_g, const float* __restrict__ Wb,
    const float* __restrict__ Wff1, const float* __restrict__ bff1,
    const float* __restrict__ Wff2, const float* __restrict__ bff2,
    const float* __restrict__ Wta,  const float* __restrict__ bta,
    const float* __restrict__ Wtb,  const float* __restrict__ btb,
    float* __restrict__ seq)
{
    __shared__ alignas(16) float h_lds[32];
    __shared__ alignas(16) float g_lds[144];   // u -> u + (u>>5)*4 (bank pad)

    const int tid = threadIdx.x;
    const int b = blockIdx.x;

    // ---- stage-1 mapping
    const int u = tid >> 2, q = tid & 3;
    float wbh[8];
#pragma unroll
    for (int i = 0; i < 8; ++i) wbh[i] = Wb[u * 544 + 512 + q * 8 + i];

    // ---- stage-2 mapping
    const int j = tid >> 4;
    const int hh = (tid >> 2) & 3;
    const int q2 = tid & 3;
    const float* Wh = (hh == 0) ? Wff1 : (hh == 1) ? Wff2 : (hh == 2) ? Wta : Wtb;
    const float* bh = (hh == 0) ? bff1 : (hh == 1) ? bff2 : (hh == 2) ? bta : btb;
    float whr[32];
#pragma unroll
    for (int k4 = 0; k4 < 8; ++k4) {
        float4 v = *reinterpret_cast<const float4*>(&Wh[j * 128 + q2 * 32 + k4 * 4]);
        whr[k4 * 4 + 0] = v.x; whr[k4 * 4 + 1] = v.y;
        whr[k4 * 4 + 2] = v.z; whr[k4 * 4 + 3] = v.w;
    }
    const float hbias = bh[j];

    if (tid < 32) h_lds[tid] = 0.0f;
    __syncthreads();

    const float* pgp = pre_g + (size_t)b * 512 * 128 + u;
    float* seqp = seq + (size_t)b * 512 * 32;

    float pgbuf[8], pgnext[8];
#pragma unroll
    for (int i = 0; i < 8; ++i) pgbuf[i] = pgp[(size_t)i * 128];

    for (int c = 0; c < 64; ++c) {
        if (c < 63) {
#pragma unroll
            for (int i = 0; i < 8; ++i)
                pgnext[i] = pgp[(size_t)((c + 1) * 8 + i) * 128];
        }
#pragma unroll
        for (int s8 = 0; s8 < 8; ++s8) {
            const int step = c * 8 + s8;
            // ---- stage 1: backbone g[u]
            float4 hv0 = *reinterpret_cast<const float4*>(&h_lds[q * 8]);
            float4 hv1 = *reinterpret_cast<const float4*>(&h_lds[q * 8 + 4]);
            float s0 = wbh[0] * hv0.x, s1 = wbh[1] * hv0.y;
            s0 = fmaf(wbh[2], hv0.z, s0); s1 = fmaf(wbh[3], hv0.w, s1);
            s0 = fmaf(wbh[4], hv1.x, s0); s1 = fmaf(wbh[5], hv1.y, s1);
            s0 = fmaf(wbh[6], hv1.z, s0); s1 = fmaf(wbh[7], hv1.w, s1);
            float s = s0 + s1;
            s += __shfl_xor(s, 1);
            s += __shfl_xor(s, 2);
            float g = 1.7159f * fast_tanh(0.666f * (pgbuf[s8] + s));
            if (q == 0) g_lds[u + ((u >> 5) << 2)] = g;
            __syncthreads();                       // B1

            // ---- stage 2: head hh of unit j, K slice q2*32..+32
            const float* gq = &g_lds[q2 * 36];
            float d0 = 0.f, d1 = 0.f, d2 = 0.f, d3 = 0.f;
#pragma unroll
            for (int k4 = 0; k4 < 8; k4 += 4) {
                float4 ga = *reinterpret_cast<const float4*>(&gq[k4 * 4]);
                float4 gb = *reinterpret_cast<const float4*>(&gq[k4 * 4 + 4]);
                float4 gc = *reinterpret_cast<const float4*>(&gq[k4 * 4 + 8]);
                float4 gd = *reinterpret_cast<const float4*>(&gq[k4 * 4 + 12]);
                d0 = fmaf(whr[k4 * 4 + 0], ga.x, d0);
                d1 = fmaf(whr[k4 * 4 + 1], ga.y, d1);
                d2 = fmaf(whr[k4 * 4 + 2], ga.z, d2);
                d3 = fmaf(whr[k4 * 4 + 3], ga.w, d3);
                d0 = fmaf(whr[k4 * 4 + 4], gb.x, d0);
                d1 = fmaf(whr[k4 * 4 + 5], gb.y, d1);
                d2 = fmaf(whr[k4 * 4 + 6], gb.z, d2);
                d3 = fmaf(whr[k4 * 4 + 7], gb.w, d3);
                d0 = fmaf(whr[k4 * 4 + 8], gc.x, d0);
                d1 = fmaf(whr[k4 * 4 + 9], gc.y, d1);
                d2 = fmaf(whr[k4 * 4 + 10], gc.z, d2);
                d3 = fmaf(whr[k4 * 4 + 11], gc.w, d3);
                d0 = fmaf(whr[k4 * 4 + 12], gd.x, d0);
                d1 = fmaf(whr[k4 * 4 + 13], gd.y, d1);
                d2 = fmaf(whr[k4 * 4 + 14], gd.z, d2);
                d3 = fmaf(whr[k4 * 4 + 15], gd.w, d3);
            }
            float d = (d0 + d1) + (d2 + d3);
            d += __shfl_xor(d, 1);
            d += __shfl_xor(d, 2);
            d += hbias;
            if (hh < 2) d = fast_tanh(d);          // ff1/ff2 tanh; ta/tb raw
            // gather within 16-lane group: for hh==0 lane -> ff1=d, ff2, ta, tb
            float vff2 = __shfl_xor(d, 4);
            float vta  = __shfl_xor(d, 8);
            float vtb  = __shfl_xor(d, 12);
            float ti = 1.0f / (1.0f + __expf(-(vta + vtb)));
            float hn = fmaf(ti, vff2 - d, d);
            if ((tid & 15) == 0) {
                h_lds[j] = hn;
                seqp[(size_t)step * 32 + j] = hn;
            }
            __syncthreads();                       // B2
        }
#pragma unroll
        for (int i = 0; i < 8; ++i) pgbuf[i] = pgnext[i];
    }
}

// ---------------------------------------------------------------------------
// Final: y=gelu(seq); logits=y@W2^T+b2; max over T; softmax -> out [128,3]
// ---------------------------------------------------------------------------
__global__ __launch_bounds__(256) void final_kernel(
    const float* __restrict__ seq, const float* __restrict__ W2,
    const float* __restrict__ b2, float* __restrict__ out)
{
    const int b = blockIdx.x, tid = threadIdx.x;
    __shared__ float w2s[96];
    __shared__ float redbuf[12];
    if (tid < 96) w2s[tid] = W2[tid];
    __syncthreads();

    float m0 = -1e30f, m1 = -1e30f, m2 = -1e30f;
    for (int t = tid; t < 512; t += 256) {
        const float* row = &seq[(size_t)(b * 512 + t) * 32];
        float l0 = 0.f, l1 = 0.f, l2 = 0.f;
#pragma unroll
        for (int u4 = 0; u4 < 8; ++u4) {
            float4 v = *reinterpret_cast<const float4*>(&row[u4 * 4]);
            float xs[4] = {v.x, v.y, v.z, v.w};
#pragma unroll
            for (int e = 0; e < 4; ++e) {
                float y = gelu_exact(xs[e]);
                int uidx = u4 * 4 + e;
                l0 = fmaf(y, w2s[uidx], l0);
                l1 = fmaf(y, w2s[32 + uidx], l1);
                l2 = fmaf(y, w2s[64 + uidx], l2);
            }
        }
        m0 = fmaxf(m0, l0); m1 = fmaxf(m1, l1); m2 = fmaxf(m2, l2);
    }
#pragma unroll
    for (int off = 32; off; off >>= 1) {
        m0 = fmaxf(m0, __shfl_xor(m0, off));
        m1 = fmaxf(m1, __shfl_xor(m1, off));
        m2 = fmaxf(m2, __shfl_xor(m2, off));
    }
    if ((tid & 63) == 0) {
        int wv = tid >> 6;
        redbuf[wv * 3 + 0] = m0; redbuf[wv * 3 + 1] = m1; redbuf[wv * 3 + 2] = m2;
    }
    __syncthreads();
    if (tid == 0) {
        float a0 = -1e30f, a1 = -1e30f, a2 = -1e30f;
        for (int i = 0; i < 4; ++i) {
            a0 = fmaxf(a0, redbuf[i * 3 + 0]);
            a1 = fmaxf(a1, redbuf[i * 3 + 1]);
            a2 = fmaxf(a2, redbuf[i * 3 + 2]);
        }
        a0 += b2[0]; a1 += b2[1]; a2 += b2[2];
        float mm = fmaxf(a0, fmaxf(a1, a2));
        float e0 = expf(a0 - mm), e1 = expf(a1 - mm), e2 = expf(a2 - mm);
        float inv = 1.0f / (e0 + e1 + e2);
        out[b * 3 + 0] = e0 * inv;
        out[b * 3 + 1] = e1 * inv;
        out[b * 3 + 2] = e2 * inv;
    }
}

// ---------------------------------------------------------------------------
extern "C" void kernel_launch(void* const* d_in, const int* in_sizes, int n_in,
                              void* d_out, int out_size, void* d_ws, size_t ws_size,
                              hipStream_t stream)
{
    const float* x    = (const float*)d_in[0];
    const float* W0   = (const float*)d_in[1];
    const float* b0   = (const float*)d_in[2];
    const float* Wb   = (const float*)d_in[3];
    const float* bb   = (const float*)d_in[4];
    const float* Wff1 = (const float*)d_in[5];
    const float* bff1 = (const float*)d_in[6];
    const float* Wff2 = (const float*)d_in[7];
    const float* bff2 = (const float*)d_in[8];
    const float* Wta  = (const float*)d_in[9];
    const float* bta  = (const float*)d_in[10];
    const float* Wtb  = (const float*)d_in[11];
    const float* btb  = (const float*)d_in[12];
    const float* W2   = (const float*)d_in[13];
    const float* b2   = (const float*)d_in[14];

    char* ws = (char*)d_ws;
    unsigned short* h0bf  = (unsigned short*)(ws);                 // 67,108,864 B
    float*          pre_g = (float*)(ws + 67108864);               // 33,554,432 B
    float*          seq   = (float*)(ws + 100663296);              //  8,388,608 B
    unsigned short* W0bf  = (unsigned short*)(ws + 109051904);     //  1,048,576 B
    unsigned short* Wbxbf = (unsigned short*)(ws + 110100480);     //    131,072 B
    (void)ws_size; (void)in_sizes; (void)n_in; (void)out_size;

    convert_weights_kernel<<<512, 256, 0, stream>>>(W0, Wb, W0bf, Wbxbf);

    // h0 = gelu(x @ W0^T + b0)  -> bf16 [65536, 512]
    gemm_kernel<4, true, true><<<2048, 256, 0, stream>>>(
        (const void*)x, W0bf, b0, (void*)h0bf, 65536, 512, 1024);

    // pre_g = h0 @ Wbx^T + bb   -> fp32 [65536, 128]
    gemm_kernel<1, false, false><<<512, 256, 0, stream>>>(
        (const void*)h0bf, Wbxbf, bb, (void*)pre_g, 65536, 128, 512);

    scan_kernel<<<128, 512, 0, stream>>>(pre_g, Wb,
        Wff1, bff1, Wff2, bff2, Wta, bta, Wtb, btb, seq);

    final_kernel<<<128, 256, 0, stream>>>(seq, W2, b2, (float*)d_out);
}